// Round 8
// baseline (169.675 us; speedup 1.0000x reference)
//
#include <hip/hip_runtime.h>
#include <math.h>

// labels = argmin_k ||c1_k||^2 - 2*x.c1_k, x = inpt[:,64:128] (131072x64),
// centers1 (1024x64). centers0 unused. Output int32 labels.
constexpr int N_ROWS   = 131072;
constexpr int INPT_DIM = 128;
constexpr int DIM      = 64;
constexpr int COL_OFF  = 64;
constexpr int NCENT    = 1024;

constexpr int TM    = 128;          // rows per block (4 waves x 32 rows, ROW-SPLIT)
constexpr int RPW   = 32;           // rows per wave
constexpr int NS    = RPW / 16;     // A-frag sets per wave (2)
constexpr int NTILE = NCENT / 16;   // 64 tiles of 16 centers
constexpr int MAXC  = 16;           // candidates/row (E~1.5 under final thresh)

typedef short short8 __attribute__((ext_vector_type(8)));
typedef float f32x4  __attribute__((ext_vector_type(4)));

// ws: [0,8192) f64 cnorm | [8192,12288) f32 cnorm | [12288,12292) maxC bits
//     [16384, 16384+131072) bf16 centers, MFMA-fragment-linear:
//     frag (tile t, khalf f) lane l: 8 bf16 at ((t*2+f)*64 + l)*8
//     = centers[t*16 + (l&15)][f*32 + (l>>4)*8 + j]   (B[n][k], m89 layout)

__device__ __forceinline__ unsigned short f2bf(float f) {
    unsigned u = __float_as_uint(f);
    u += 0x7fff + ((u >> 16) & 1);          // round-to-nearest-even
    return (unsigned short)(u >> 16);
}

__device__ __forceinline__ double exact_score(const float* __restrict__ c,
                                              const float* __restrict__ x, double cn) {
    double acc = 0.0;
#pragma unroll
    for (int d = 0; d < DIM; ++d)
        acc = fma((double)c[d], (double)x[d], acc);
    return fma(-2.0, acc, cn);
}

// ---------------------------------------------------------------------------
// Prep (R0 version, proven): 4 threads per center (4096 threads, 16x256).
// Each thread reads a contiguous 64B quarter-row (coalesced), shuffle-
// combines the norm over the 4 lanes, writes its 2 fragment-quads.
// ---------------------------------------------------------------------------
__global__ __launch_bounds__(256) void prep_kernel(const float* __restrict__ centers,
                                                   double* __restrict__ cnorm_d,
                                                   float* __restrict__ cnorm_f,
                                                   int* __restrict__ maxc_i,
                                                   unsigned short* __restrict__ cbf) {
    int tid = blockIdx.x * 256 + threadIdx.x;   // 0..4095
    int k = tid >> 2, kq = tid & 3;             // center, quarter
    const float* c = centers + (size_t)k * DIM + kq * 16;
    float cf[16];
    double sd = 0.0;
#pragma unroll
    for (int j = 0; j < 4; ++j) {
        float4 v = *reinterpret_cast<const float4*>(c + j * 4);
        cf[j * 4] = v.x; cf[j * 4 + 1] = v.y; cf[j * 4 + 2] = v.z; cf[j * 4 + 3] = v.w;
        sd = fma((double)v.x, (double)v.x, sd);
        sd = fma((double)v.y, (double)v.y, sd);
        sd = fma((double)v.z, (double)v.z, sd);
        sd = fma((double)v.w, (double)v.w, sd);
    }
    // the 4 lanes of one center are adjacent (tid = k*4+kq): xor-combine norm
    sd += __shfl_xor(sd, 1);
    sd += __shfl_xor(sd, 2);
    if (kq == 0) { cnorm_d[k] = sd; cnorm_f[k] = (float)sd; }

    // dims [kq*16, kq*16+16) -> khalf f = kq>>1, quads qq = (kq&1)*2 + h
    int t = k >> 4, n = k & 15, f = kq >> 1;
#pragma unroll
    for (int h = 0; h < 2; ++h) {
        int qq = (kq & 1) * 2 + h;
        const float* s = cf + h * 8;
        uint4 w;
        w.x = (unsigned)f2bf(s[0]) | ((unsigned)f2bf(s[1]) << 16);
        w.y = (unsigned)f2bf(s[2]) | ((unsigned)f2bf(s[3]) << 16);
        w.z = (unsigned)f2bf(s[4]) | ((unsigned)f2bf(s[5]) << 16);
        w.w = (unsigned)f2bf(s[6]) | ((unsigned)f2bf(s[7]) << 16);
        *reinterpret_cast<uint4*>(cbf + ((size_t)((t * 2 + f) * 64 + qq * 16 + n)) * 8) = w;
    }
    float nm = sqrtf((float)sd);
#pragma unroll
    for (int mk = 1; mk < 64; mk <<= 1)
        nm = fmaxf(nm, __shfl_xor(nm, mk));
    if ((threadIdx.x & 63) == 0) atomicMax(maxc_i, __float_as_int(nm));  // poison<0 loses
}

// ---------------------------------------------------------------------------
// Main v8: ROW-SPLIT 4-wave pack. R7 post-mortem: single-wave workgroups
// saturate at ~8 WG/CU regardless of grid (2048 vs 4096 blocks -> 19.6% vs
// 22.9% occ) -- residency is WG-slot-capped, so the only way to more waves
// is more waves PER workgroup. The 186us center-split family coupled waves
// via mid-kernel barriers + shared thresholds; v8 instead glues 4 fully
// INDEPENDENT copies of the proven R7 per-wave body into one block: wave wv
// owns rows [wv*32, wv*32+32), streams all 64 B-tiles itself (identical
// loadGroup/comp1/comp2/resolve), candidates and thresholds never cross
// waves. Shared: A-staging + cn_lds (one barrier) + one safety barrier
// before resolve. TM=128 -> grid 1024 = 4 blocks/CU x 4 waves = 16 waves/CU
// target (2.3x R7), LDS 31.7KB (5/CU fits), VGPR ~90 (under the measured
// (256,2)->128 clamp; no spills). Per-row B traffic unchanged vs R7.
// ---------------------------------------------------------------------------
__global__ __launch_bounds__(256, 2) void label_kernel(
        const float* __restrict__ inpt, const float* __restrict__ centers,
        const double* __restrict__ cnorm_d, const float* __restrict__ cnorm_f,
        const int* __restrict__ maxc_i, const unsigned short* __restrict__ cbf,
        int* __restrict__ out) {
    __shared__ unsigned short A_lds[TM][72];   // 144B rows: frag reads 2-way (free)
    __shared__ float cn_lds[NCENT];
    __shared__ float margin_lds[TM];
    __shared__ int   cand[TM][MAXC];
    __shared__ int   ccount[TM];

    const int t    = threadIdx.x;              // 0..255
    const int lane = t & 63;
    const int wv   = t >> 6;                   // wave id 0..3
    const int rowBase = blockIdx.x * TM;

    // ---- stage: 2 threads per row (t>>1 = row 0..127), 128B halves, coalesced
    {
        const int row = t >> 1, hf = t & 1;
        const float* xp = inpt + (size_t)(rowBase + row) * INPT_DIM + COL_OFF + hf * 32;
        float nx2 = 0.f;
#pragma unroll
        for (int j = 0; j < 8; ++j) {
            float4 v = *reinterpret_cast<const float4*>(xp + j * 4);
            nx2 = fmaf(v.x, v.x, fmaf(v.y, v.y, fmaf(v.z, v.z, fmaf(v.w, v.w, nx2))));
            unsigned u0 = (unsigned)f2bf(v.x) | ((unsigned)f2bf(v.y) << 16);
            unsigned u1 = (unsigned)f2bf(v.z) | ((unsigned)f2bf(v.w) << 16);
            int col = hf * 32 + j * 4;
            *reinterpret_cast<unsigned*>(&A_lds[row][col])     = u0;
            *reinterpret_cast<unsigned*>(&A_lds[row][col + 2]) = u1;
        }
        // half-norm combine: lanes 2r, 2r+1 of the same wave share the row
        nx2 += __shfl_xor(nx2, 1);
        // bf16 score err <= 2^-7|x||c| each way; formula unchanged since R3 (absmax=0)
        if (hf == 0)
            margin_lds[row] = (1.5f / 64.f) * sqrtf(nx2) * __int_as_float(maxc_i[0]) + 1e-3f;
        if (t < TM) ccount[t] = 0;
        *reinterpret_cast<float4*>(&cn_lds[t * 4]) =
            *reinterpret_cast<const float4*>(cnorm_f + t * 4);
    }
    __syncthreads();

    const int m = lane & 15, q = lane >> 4;
    const int wrow = wv * RPW;                 // this wave's first row
    short8 af0[NS], af1[NS];   // m89: A[m=lane&15][k=q*8+j]; 2 sets of 16 rows
#pragma unroll
    for (int s = 0; s < NS; ++s) {
        af0[s] = *reinterpret_cast<const short8*>(&A_lds[wrow + s * 16 + m][q * 8]);
        af1[s] = *reinterpret_cast<const short8*>(&A_lds[wrow + s * 16 + m][32 + q * 8]);
    }

    const short8* bfrag = reinterpret_cast<const short8*>(cbf);

    auto loadGroup = [&](short8 (&B0)[4], short8 (&B1)[4], float (&CN)[4], int tb) {
#pragma unroll
        for (int j = 0; j < 4; ++j) {
            B0[j] = bfrag[((tb + j) * 2 + 0) * 64 + lane];
            B1[j] = bfrag[((tb + j) * 2 + 1) * 64 + lane];
            CN[j] = cn_lds[(tb + j) * 16 + m];
        }
    };

    // ================= pass 1: running min only (all 64 tiles) =============
    float rmin[NS][4];
#pragma unroll
    for (int s = 0; s < NS; ++s)
#pragma unroll
        for (int r4 = 0; r4 < 4; ++r4) rmin[s][r4] = INFINITY;

    auto comp1 = [&](short8 (&B0)[4], short8 (&B1)[4], float (&CN)[4]) {
#pragma unroll
        for (int j = 0; j < 4; ++j) {
#pragma unroll
            for (int s = 0; s < NS; ++s) {
                f32x4 acc = {0.f, 0.f, 0.f, 0.f};
                acc = __builtin_amdgcn_mfma_f32_16x16x32_bf16(af0[s], B0[j], acc, 0, 0, 0);
                acc = __builtin_amdgcn_mfma_f32_16x16x32_bf16(af1[s], B1[j], acc, 0, 0, 0);
#pragma unroll
                for (int r4 = 0; r4 < 4; ++r4)   // D: col=m (center), row=q*4+r4
                    rmin[s][r4] = fminf(rmin[s][r4], fmaf(-2.f, acc[r4], CN[j]));
            }
        }
    };

    {
        short8 X0[4], X1[4], Y0[4], Y1[4];
        float  XC[4], YC[4];
        loadGroup(X0, X1, XC, 0);
        for (int gp = 0; gp < 8; ++gp) {          // dynamic loop: buffers stay regs
            int t0 = gp * 8;
            loadGroup(Y0, Y1, YC, t0 + 4);        // prefetch while computing X
            comp1(X0, X1, XC);
            if (gp < 7) loadGroup(X0, X1, XC, t0 + 8);
            comp1(Y0, Y1, YC);
        }
    }

    // ---- one cross-lane reduction (16-lane m-groups) -> per-row thresholds
    //      (rows owned by this wave only -- no cross-wave exchange)
    float thresh[NS][4], tmax[NS];
    float tmax_all = -INFINITY;
#pragma unroll
    for (int s = 0; s < NS; ++s) {
        tmax[s] = -INFINITY;
#pragma unroll
        for (int r4 = 0; r4 < 4; ++r4) {
            float v = rmin[s][r4];
            v = fminf(v, __shfl_xor(v, 1));
            v = fminf(v, __shfl_xor(v, 2));
            v = fminf(v, __shfl_xor(v, 4));
            v = fminf(v, __shfl_xor(v, 8));
            v += margin_lds[wrow + s * 16 + q * 4 + r4];
            thresh[s][r4] = v;
            tmax[s] = fmaxf(tmax[s], v);
        }
        tmax_all = fmaxf(tmax_all, tmax[s]);
    }

    // ================= pass 2: recompute + append candidates =================
    auto comp2 = [&](short8 (&B0)[4], short8 (&B1)[4], float (&CN)[4], int tb) {
#pragma unroll
        for (int j = 0; j < 4; ++j) {
            f32x4 sc[NS];
            float cmin = INFINITY;
#pragma unroll
            for (int s = 0; s < NS; ++s) {
                f32x4 acc = {0.f, 0.f, 0.f, 0.f};
                acc = __builtin_amdgcn_mfma_f32_16x16x32_bf16(af0[s], B0[j], acc, 0, 0, 0);
                acc = __builtin_amdgcn_mfma_f32_16x16x32_bf16(af1[s], B1[j], acc, 0, 0, 0);
#pragma unroll
                for (int r4 = 0; r4 < 4; ++r4) {
                    sc[s][r4] = fmaf(-2.f, acc[r4], CN[j]);
                    cmin = fminf(cmin, sc[s][r4]);
                }
            }
            if (cmin < tmax_all) {
#pragma unroll
                for (int s = 0; s < NS; ++s) {
                    float smin = fminf(fminf(sc[s][0], sc[s][1]), fminf(sc[s][2], sc[s][3]));
                    if (smin < tmax[s]) {
#pragma unroll
                        for (int r4 = 0; r4 < 4; ++r4) {
                            if (sc[s][r4] < thresh[s][r4]) {   // pass1==pass2 scores (determinism)
                                int row = wrow + s * 16 + q * 4 + r4;
                                int slot = atomicAdd(&ccount[row], 1);
                                if (slot < MAXC) cand[row][slot] = (tb + j) * 16 + m;
                            }
                        }
                    }
                }
            }
        }
    };

    {
        short8 X0[4], X1[4], Y0[4], Y1[4];
        float  XC[4], YC[4];
        loadGroup(X0, X1, XC, 0);
        for (int gp = 0; gp < 8; ++gp) {
            int t0 = gp * 8;
            loadGroup(Y0, Y1, YC, t0 + 4);
            comp2(X0, X1, XC, t0);
            if (gp < 7) loadGroup(X0, X1, XC, t0 + 8);
            comp2(Y0, Y1, YC, t0 + 4);
        }
    }
    __syncthreads();   // safety: LDS cand/ccount visibility before resolve

    // ---- exact f64 resolve: wave wv resolves its own rows; lane r (<32)
    //      resolves row wrow+r (argmin with k-tie-break is order-independent)
    if (lane < RPW) {
        int row = wrow + lane;
        int cnt = ccount[row];
        int best;
        if (cnt == 1) {
            best = cand[row][0];
        } else {
            const float* xp = inpt + (size_t)(rowBase + row) * INPT_DIM + COL_OFF;
            double bestv = 1e300;
            best = 0x7fffffff;
            if (cnt <= MAXC) {
                for (int j = 0; j < cnt; ++j) {
                    int k = cand[row][j];
                    double s = exact_score(centers + (size_t)k * DIM, xp, cnorm_d[k]);
                    if (s < bestv || (s == bestv && k < best)) { bestv = s; best = k; }
                }
            } else {  // overflow fallback: full exact scan (P ~ 0)
                for (int k = 0; k < NCENT; ++k) {
                    double s = exact_score(centers + (size_t)k * DIM, xp, cnorm_d[k]);
                    if (s < bestv) { bestv = s; best = k; }
                }
            }
        }
        out[rowBase + row] = best;
    }
}

// ---------------------------------------------------------------------------
extern "C" void kernel_launch(void* const* d_in, const int* in_sizes, int n_in,
                              void* d_out, int out_size, void* d_ws, size_t ws_size,
                              hipStream_t stream) {
    const float* inpt     = (const float*)d_in[0];
    const float* centers1 = (const float*)d_in[2];   // centers0 (d_in[1]) unused
    int* out = (int*)d_out;

    char* ws = (char*)d_ws;
    double* cnorm_d = (double*)ws;
    float*  cnorm_f = (float*)(ws + 8192);
    int*    maxc_i  = (int*)(ws + 12288);
    unsigned short* cbf = (unsigned short*)(ws + 16384);

    prep_kernel<<<16, 256, 0, stream>>>(centers1, cnorm_d, cnorm_f, maxc_i, cbf);
    label_kernel<<<N_ROWS / TM, 256, 0, stream>>>(inpt, centers1, cnorm_d, cnorm_f,
                                                  maxc_i, cbf, out);
}